// Round 3
// baseline (985.040 us; speedup 1.0000x reference)
//
#include <hip/hip_runtime.h>
#include <math.h>

#define BB 8
#define NN 2048
#define FF 256
#define NW 64            // packed u32 words per adjacency row
#define ALPHA 0.2f

typedef _Float16 f16x8 __attribute__((ext_vector_type(8)));
typedef _Float16 f16x4 __attribute__((ext_vector_type(4)));
typedef float    f32x4 __attribute__((ext_vector_type(4)));

__device__ __forceinline__ float lrelu(float x){ return fmaxf(x, ALPHA*x); }

// ---------------------------------------------------------------- pack adj bits + x->f16
__global__ void pack_adj(const int* __restrict__ adj, unsigned long long* __restrict__ packed,
                         const float* __restrict__ x, _Float16* __restrict__ h0){
    long long idx = (long long)blockIdx.x*blockDim.x + threadIdx.x;
    long long stride = (long long)gridDim.x*blockDim.x;
    const long long total = (long long)BB*NN*NN;
    for (long long i = idx; i < total; i += stride){
        unsigned long long m = __ballot(adj[i] > 0);
        if ((threadIdx.x & 63) == 0) packed[i >> 6] = m;
    }
    const long long nx4 = (long long)BB*NN*FF/4;
    for (long long i = idx; i < nx4; i += stride){
        float4 v = ((const float4*)x)[i];
        union { _Float16 h[4]; unsigned long long u; } cv;
        cv.h[0] = (_Float16)v.x; cv.h[1] = (_Float16)v.y;
        cv.h[2] = (_Float16)v.z; cv.h[3] = (_Float16)v.w;
        ((unsigned long long*)h0)[i] = cv.u;
    }
}

// ---------------------------------------------------------------- W (fp32 [k][c]) -> Wt (f16 [c][k]), 4 layers
__global__ void prep_w(const float* __restrict__ W0, const float* __restrict__ Wrest,
                       _Float16* __restrict__ Wt){
    __shared__ _Float16 Ls[64][66];
    int layer = blockIdx.z;
    int c0 = blockIdx.x * 64, k0 = blockIdx.y * 64;
    const float* Win = (layer == 0) ? W0 : (Wrest + (size_t)(layer-1)*FF*FF);
    int t = threadIdx.x;
    for (int it = 0; it < 4; ++it){
        int idx = it*256 + t;
        int r = idx >> 4, c4 = (idx & 15) * 4;
        float4 v = *(const float4*)&Win[(size_t)(k0 + r)*FF + c0 + c4];
        Ls[c4+0][r] = (_Float16)v.x; Ls[c4+1][r] = (_Float16)v.y;
        Ls[c4+2][r] = (_Float16)v.z; Ls[c4+3][r] = (_Float16)v.w;
    }
    __syncthreads();
    int c = t >> 2, jch = t & 3;
    const unsigned* lp = (const unsigned*)&Ls[c][jch*16];
    int4 o0 = make_int4(lp[0], lp[1], lp[2], lp[3]);
    int4 o1 = make_int4(lp[4], lp[5], lp[6], lp[7]);
    _Float16* dst = Wt + ((size_t)layer*FF + c0 + c)*FF + k0 + jch*16;
    *(int4*)dst = o0;
    *(int4*)(dst + 8) = o1;
}

// ---------------------------------------------------------------- WhT = (h @ W)^T (f16 MFMA) + fused f1,f2
__global__ __launch_bounds__(512,2) void gemm_hw(const _Float16* __restrict__ hin,
        const _Float16* __restrict__ Wt, const float* __restrict__ Avec,
        _Float16* __restrict__ WhT, float* __restrict__ f1, float* __restrict__ f2){
    __shared__ float fred[2][64][4];
    int t = threadIdx.x, l = t & 63, wid = t >> 6;
    int wr = wid >> 2, wc = wid & 3;
    int lg = l >> 4, lr = l & 15;
    size_t i0 = (size_t)blockIdx.x * 64;
    f32x4 acc[2][4] = {};
    for (int k0 = 0; k0 < FF; k0 += 32){
        f16x8 a[2], bf[4];
        #pragma unroll
        for (int m = 0; m < 2; ++m){
            int4 v = *(const int4*)&hin[(i0 + wr*32 + m*16 + lr)*FF + k0 + lg*8];
            a[m] = *(f16x8*)&v;
        }
        #pragma unroll
        for (int n = 0; n < 4; ++n){
            int4 v = *(const int4*)&Wt[(size_t)(wc*64 + n*16 + lr)*FF + k0 + lg*8];
            bf[n] = *(f16x8*)&v;
        }
        #pragma unroll
        for (int m = 0; m < 2; ++m)
            #pragma unroll
            for (int n = 0; n < 4; ++n)
                acc[m][n] = __builtin_amdgcn_mfma_f32_16x16x32_f16(a[m], bf[n], acc[m][n], 0, 0, 0);
    }
    // transposed store: WhT[b][col][row] (f16x4 along rows)
    int b  = (int)(i0 >> 11);
    int jb = (int)(i0 & (NN-1));
    _Float16* WT = WhT + (size_t)b*FF*NN;
    #pragma unroll
    for (int m = 0; m < 2; ++m){
        #pragma unroll
        for (int n = 0; n < 4; ++n){
            int col = wc*64 + n*16 + lr;
            int row = jb + wr*32 + m*16 + lg*4;
            f16x4 pk;
            pk[0] = (_Float16)acc[m][n][0]; pk[1] = (_Float16)acc[m][n][1];
            pk[2] = (_Float16)acc[m][n][2]; pk[3] = (_Float16)acc[m][n][3];
            *(f16x4*)&WT[(size_t)col*NN + row] = pk;
        }
    }
    // fused f1/f2 (fp32 from accumulators)
    float a1v[4], a2v[4];
    #pragma unroll
    for (int n = 0; n < 4; ++n){
        a1v[n] = Avec[wc*64 + n*16 + lr];
        a2v[n] = Avec[FF + wc*64 + n*16 + lr];
    }
    #pragma unroll
    for (int m = 0; m < 2; ++m){
        #pragma unroll
        for (int q = 0; q < 4; ++q){
            float p1 = 0.f, p2 = 0.f;
            #pragma unroll
            for (int n = 0; n < 4; ++n){
                float v = acc[m][n][q];
                p1 = fmaf(v, a1v[n], p1);
                p2 = fmaf(v, a2v[n], p2);
            }
            #pragma unroll
            for (int msk = 1; msk < 16; msk <<= 1){
                p1 += __shfl_xor(p1, msk);
                p2 += __shfl_xor(p2, msk);
            }
            if (lr == 0){
                fred[0][wr*32 + m*16 + lg*4 + q][wc] = p1;
                fred[1][wr*32 + m*16 + lg*4 + q][wc] = p2;
            }
        }
    }
    __syncthreads();
    if (t < 128){
        int row = t & 63, f = t >> 6;
        float v = fred[f][row][0] + fred[f][row][1] + fred[f][row][2] + fred[f][row][3];
        (f ? f2 : f1)[i0 + row] = v;
    }
}

// ---------------------------------------------------------------- spart[b][it][j] = sum_{i in it} adj ? exp(lrelu(f1_i+f2_j)) : 0
__global__ void spass(const unsigned* __restrict__ packed, const float* __restrict__ f1,
                      const float* __restrict__ f2, float* __restrict__ spart){
    __shared__ float sred[4][512];
    int jt = blockIdx.x, it = blockIdx.y, b = blockIdx.z;
    int t = threadIdx.x;
    int ti = t >> 6, jc = t & 63;
    int j0 = jt*512 + jc*8;
    const unsigned* pb = packed + (size_t)b*NN*NW;
    const float* f1b = f1 + b*NN;
    float f2v[8];
    *(float4*)&f2v[0] = *(const float4*)&f2[b*NN + j0];
    *(float4*)&f2v[4] = *(const float4*)&f2[b*NN + j0 + 4];
    int sh = (jc & 3) * 8;
    float acc[8] = {};
    for (int ii = 0; ii < 64; ++ii){
        int i = it*256 + ti*64 + ii;
        unsigned w = pb[(size_t)i*NW + (j0 >> 5)] >> sh;
        float f1v = f1b[i];
        #pragma unroll
        for (int e = 0; e < 8; ++e){
            float xv = f1v + f2v[e];
            float p = __expf(fmaxf(xv, ALPHA*xv));
            acc[e] += ((w >> e) & 1u) ? p : 0.f;
        }
    }
    #pragma unroll
    for (int e = 0; e < 8; ++e) sred[ti][jc*8 + e] = acc[e];
    __syncthreads();
    if (ti == 0){
        #pragma unroll
        for (int e = 0; e < 8; ++e){
            float s = sred[0][jc*8+e] + sred[1][jc*8+e] + sred[2][jc*8+e] + sred[3][jc*8+e];
            spart[((size_t)b*8 + it)*NN + j0 + e] = s;
        }
    }
}

// ---------------------------------------------------------------- E[i][j] = adj ? exp(lrelu(f1+f2) - ln s_j) : 0  (f16, normalized)
__global__ void epass(const unsigned* __restrict__ packed, const float* __restrict__ f1,
                      const float* __restrict__ f2, const float* __restrict__ spart,
                      _Float16* __restrict__ E){
    int it = blockIdx.x, b = blockIdx.y;
    int t = threadIdx.x;
    int j0 = t*8;
    float f2v[8], gv[8];
    *(float4*)&f2v[0] = *(const float4*)&f2[b*NN + j0];
    *(float4*)&f2v[4] = *(const float4*)&f2[b*NN + j0 + 4];
    float sa[8] = {};
    #pragma unroll
    for (int p8 = 0; p8 < 8; ++p8){
        float4 v0 = *(const float4*)&spart[((size_t)b*8 + p8)*NN + j0];
        float4 v1 = *(const float4*)&spart[((size_t)b*8 + p8)*NN + j0 + 4];
        sa[0] += v0.x; sa[1] += v0.y; sa[2] += v0.z; sa[3] += v0.w;
        sa[4] += v1.x; sa[5] += v1.y; sa[6] += v1.z; sa[7] += v1.w;
    }
    #pragma unroll
    for (int e = 0; e < 8; ++e) gv[e] = -__logf(sa[e]);
    const unsigned* pb = packed + (size_t)b*NN*NW;
    const float* f1b = f1 + b*NN;
    int sh = (t & 3) * 8;
    int i0 = it*32;
    for (int ii = 0; ii < 32; ++ii){
        int i = i0 + ii;
        unsigned w = pb[(size_t)i*NW + (j0 >> 5)] >> sh;
        float f1v = f1b[i];
        f16x8 ev;
        #pragma unroll
        for (int e = 0; e < 8; ++e){
            float xv = f1v + f2v[e];
            float p = __expf(fmaxf(xv, ALPHA*xv) + gv[e]);
            ev[e] = (_Float16)(((w >> e) & 1u) ? p : 0.f);
        }
        *(int4*)&E[((size_t)b*NN + i)*NN + j0] = *(int4*)&ev;
    }
}

// ---------------------------------------------------------------- hout = lrelu( E @ WhT^T ): pure f16 GEMM
__global__ __launch_bounds__(256,4) void gemm_att(const _Float16* __restrict__ E,
        const _Float16* __restrict__ WhT, _Float16* __restrict__ hnext,
        float* __restrict__ out, int last){
    __shared__ char Bs[16*1024];
    int t = threadIdx.x, l = t & 63, wc = t >> 6;
    int lg = l >> 4, lr = l & 15;
    // decode: each XCD (blockIdx%8) owns one batch; c0-pairs adjacent
    int w   = blockIdx.x;
    int k   = w & 7, seq = w >> 3;
    int p   = k*64 + (seq >> 1);
    int c0  = (seq & 1) * 128;
    int b   = p >> 6;
    int i0  = (p & 63) * 32;
    const _Float16* Eb = E + ((size_t)b*NN + i0)*NN;
    const _Float16* WT = WhT + (size_t)b*FF*NN + (size_t)c0*NN;
    f32x4 acc[2][2] = {};
    for (int ks = 0; ks < 32; ++ks){
        int j0 = ks*64;
        // issue global loads first (B stage regs + A fragments)
        int4 stg[4];
        #pragma unroll
        for (int q = 0; q < 4; ++q){
            int idx = q*256 + t;
            int col = idx >> 3, ch = idx & 7;
            stg[q] = *(const int4*)&WT[(size_t)col*NN + j0 + ch*8];
        }
        f16x8 pa[2][2];
        #pragma unroll
        for (int m = 0; m < 2; ++m)
            #pragma unroll
            for (int kk = 0; kk < 2; ++kk){
                int4 v = *(const int4*)&Eb[(size_t)(m*16 + lr)*NN + j0 + kk*32 + lg*8];
                pa[m][kk] = *(f16x8*)&v;
            }
        __syncthreads();   // previous iteration's ds_reads complete
        #pragma unroll
        for (int q = 0; q < 4; ++q){
            int idx = q*256 + t;
            int col = idx >> 3, ch = idx & 7;
            *(int4*)(Bs + (col << 7) + ((ch << 4) ^ ((col & 7) << 4))) = stg[q];
        }
        __syncthreads();
        #pragma unroll
        for (int n = 0; n < 2; ++n){
            int col = wc*32 + n*16 + lr;
            #pragma unroll
            for (int kk = 0; kk < 2; ++kk){
                f16x8 bf = *(const f16x8*)(Bs + (col << 7) + ((kk*64 + lg*16) ^ ((col & 7) << 4)));
                #pragma unroll
                for (int m = 0; m < 2; ++m)
                    acc[m][n] = __builtin_amdgcn_mfma_f32_16x16x32_f16(pa[m][kk], bf, acc[m][n], 0, 0, 0);
            }
        }
    }
    size_t obase = (size_t)b*NN*FF;
    #pragma unroll
    for (int m = 0; m < 2; ++m){
        #pragma unroll
        for (int q = 0; q < 4; ++q){
            size_t row = i0 + m*16 + lg*4 + q;
            #pragma unroll
            for (int n = 0; n < 2; ++n){
                int col = c0 + wc*32 + n*16 + lr;
                float v = lrelu(acc[m][n][q]);
                if (last) out[obase + row*FF + col] = v;
                else      hnext[obase + row*FF + col] = (_Float16)v;
            }
        }
    }
}

// ----------------------------------------------------------------
extern "C" void kernel_launch(void* const* d_in, const int* in_sizes, int n_in,
                              void* d_out, int out_size, void* d_ws, size_t ws_size,
                              hipStream_t stream){
    const float* x     = (const float*)d_in[0];
    const int*   adj   = (const int*)  d_in[1];
    const float* W0    = (const float*)d_in[2];
    const float* Wrest = (const float*)d_in[3];
    const float* A     = (const float*)d_in[4];
    float* out = (float*)d_out;

    char* ws = (char*)d_ws;
    size_t off = 0;
    auto carve = [&](size_t bytes) -> void* {
        void* p = ws + off;
        off += (bytes + 255) & ~(size_t)255;
        return p;
    };
    unsigned long long* packed = (unsigned long long*)carve((size_t)BB*NN*NN/8);
    _Float16* E    = (_Float16*)carve((size_t)BB*NN*NN*2);    // 67 MB normalized attention
    _Float16* hA   = (_Float16*)carve((size_t)BB*NN*FF*2);
    _Float16* hB   = (_Float16*)carve((size_t)BB*NN*FF*2);
    _Float16* WhT  = (_Float16*)carve((size_t)BB*NN*FF*2);
    _Float16* Wt   = (_Float16*)carve((size_t)4*FF*FF*2);
    float* f1    = (float*)carve((size_t)BB*NN*4);
    float* f2    = (float*)carve((size_t)BB*NN*4);
    float* spart = (float*)carve((size_t)BB*8*NN*4);

    pack_adj<<<2048, 256, 0, stream>>>(adj, packed, x, hA);
    prep_w<<<dim3(4,4,4), 256, 0, stream>>>(W0, Wrest, Wt);

    _Float16* bufs[2] = {hA, hB};
    const _Float16* hin = hA;
    for (int layer = 0; layer < 4; ++layer){
        const float* Al = A + (size_t)layer*2*FF;
        gemm_hw<<<256, 512, 0, stream>>>(hin, Wt + (size_t)layer*FF*FF, Al, WhT, f1, f2);
        spass<<<dim3(4,8,8), 256, 0, stream>>>((const unsigned*)packed, f1, f2, spart);
        epass<<<dim3(64,8), 256, 0, stream>>>((const unsigned*)packed, f1, f2, spart, E);
        int last = (layer == 3);
        _Float16* hnext = bufs[(layer + 1) & 1];
        gemm_att<<<1024, 256, 0, stream>>>(E, WhT, hnext, out, last);
        hin = hnext;
    }
}

// Round 4
// 976.439 us; speedup vs baseline: 1.0088x; 1.0088x over previous
//
#include <hip/hip_runtime.h>
#include <math.h>

#define BB 8
#define NN 2048
#define FF 256
#define NW 64            // packed u32 words per adjacency row
#define ALPHA 0.2f

typedef _Float16 f16x8 __attribute__((ext_vector_type(8)));
typedef _Float16 f16x4 __attribute__((ext_vector_type(4)));
typedef float    f32x4 __attribute__((ext_vector_type(4)));

__device__ __forceinline__ float lrelu(float x){ return fmaxf(x, ALPHA*x); }

// ---------------------------------------------------------------- pack adj bits + x->f16
__global__ void pack_adj(const int* __restrict__ adj, unsigned long long* __restrict__ packed,
                         const float* __restrict__ x, _Float16* __restrict__ h0){
    long long idx = (long long)blockIdx.x*blockDim.x + threadIdx.x;
    long long stride = (long long)gridDim.x*blockDim.x;
    const long long total = (long long)BB*NN*NN;
    for (long long i = idx; i < total; i += stride){
        unsigned long long m = __ballot(adj[i] > 0);
        if ((threadIdx.x & 63) == 0) packed[i >> 6] = m;
    }
    const long long nx4 = (long long)BB*NN*FF/4;
    for (long long i = idx; i < nx4; i += stride){
        float4 v = ((const float4*)x)[i];
        union { _Float16 h[4]; unsigned long long u; } cv;
        cv.h[0] = (_Float16)v.x; cv.h[1] = (_Float16)v.y;
        cv.h[2] = (_Float16)v.z; cv.h[3] = (_Float16)v.w;
        ((unsigned long long*)h0)[i] = cv.u;
    }
}

// ---------------------------------------------------------------- W (fp32 [k][c]) -> Wt (f16 [c][k]), 4 layers
__global__ void prep_w(const float* __restrict__ W0, const float* __restrict__ Wrest,
                       _Float16* __restrict__ Wt){
    __shared__ _Float16 Ls[64][66];
    int layer = blockIdx.z;
    int c0 = blockIdx.x * 64, k0 = blockIdx.y * 64;
    const float* Win = (layer == 0) ? W0 : (Wrest + (size_t)(layer-1)*FF*FF);
    int t = threadIdx.x;
    for (int it = 0; it < 4; ++it){
        int idx = it*256 + t;
        int r = idx >> 4, c4 = (idx & 15) * 4;
        float4 v = *(const float4*)&Win[(size_t)(k0 + r)*FF + c0 + c4];
        Ls[c4+0][r] = (_Float16)v.x; Ls[c4+1][r] = (_Float16)v.y;
        Ls[c4+2][r] = (_Float16)v.z; Ls[c4+3][r] = (_Float16)v.w;
    }
    __syncthreads();
    int c = t >> 2, jch = t & 3;
    const unsigned* lp = (const unsigned*)&Ls[c][jch*16];
    int4 o0 = make_int4(lp[0], lp[1], lp[2], lp[3]);
    int4 o1 = make_int4(lp[4], lp[5], lp[6], lp[7]);
    _Float16* dst = Wt + ((size_t)layer*FF + c0 + c)*FF + k0 + jch*16;
    *(int4*)dst = o0;
    *(int4*)(dst + 8) = o1;
}

// ---------------------------------------------------------------- WhT = (h @ W)^T (f16 MFMA) + fused f1,f2
__global__ __launch_bounds__(512,2) void gemm_hw(const _Float16* __restrict__ hin,
        const _Float16* __restrict__ Wt, const float* __restrict__ Avec,
        _Float16* __restrict__ WhT, float* __restrict__ f1, float* __restrict__ f2){
    __shared__ float fred[2][64][4];
    int t = threadIdx.x, l = t & 63, wid = t >> 6;
    int wr = wid >> 2, wc = wid & 3;
    int lg = l >> 4, lr = l & 15;
    size_t i0 = (size_t)blockIdx.x * 64;
    f32x4 acc[2][4] = {};
    for (int k0 = 0; k0 < FF; k0 += 32){
        f16x8 a[2], bf[4];
        #pragma unroll
        for (int m = 0; m < 2; ++m){
            int4 v = *(const int4*)&hin[(i0 + wr*32 + m*16 + lr)*FF + k0 + lg*8];
            a[m] = *(f16x8*)&v;
        }
        #pragma unroll
        for (int n = 0; n < 4; ++n){
            int4 v = *(const int4*)&Wt[(size_t)(wc*64 + n*16 + lr)*FF + k0 + lg*8];
            bf[n] = *(f16x8*)&v;
        }
        #pragma unroll
        for (int m = 0; m < 2; ++m)
            #pragma unroll
            for (int n = 0; n < 4; ++n)
                acc[m][n] = __builtin_amdgcn_mfma_f32_16x16x32_f16(a[m], bf[n], acc[m][n], 0, 0, 0);
    }
    // transposed store: WhT[b][col][row] (f16x4 along rows)
    int b  = (int)(i0 >> 11);
    int jb = (int)(i0 & (NN-1));
    _Float16* WT = WhT + (size_t)b*FF*NN;
    #pragma unroll
    for (int m = 0; m < 2; ++m){
        #pragma unroll
        for (int n = 0; n < 4; ++n){
            int col = wc*64 + n*16 + lr;
            int row = jb + wr*32 + m*16 + lg*4;
            f16x4 pk;
            pk[0] = (_Float16)acc[m][n][0]; pk[1] = (_Float16)acc[m][n][1];
            pk[2] = (_Float16)acc[m][n][2]; pk[3] = (_Float16)acc[m][n][3];
            *(f16x4*)&WT[(size_t)col*NN + row] = pk;
        }
    }
    // fused f1/f2 (fp32 from accumulators)
    float a1v[4], a2v[4];
    #pragma unroll
    for (int n = 0; n < 4; ++n){
        a1v[n] = Avec[wc*64 + n*16 + lr];
        a2v[n] = Avec[FF + wc*64 + n*16 + lr];
    }
    #pragma unroll
    for (int m = 0; m < 2; ++m){
        #pragma unroll
        for (int q = 0; q < 4; ++q){
            float p1 = 0.f, p2 = 0.f;
            #pragma unroll
            for (int n = 0; n < 4; ++n){
                float v = acc[m][n][q];
                p1 = fmaf(v, a1v[n], p1);
                p2 = fmaf(v, a2v[n], p2);
            }
            #pragma unroll
            for (int msk = 1; msk < 16; msk <<= 1){
                p1 += __shfl_xor(p1, msk);
                p2 += __shfl_xor(p2, msk);
            }
            if (lr == 0){
                fred[0][wr*32 + m*16 + lg*4 + q][wc] = p1;
                fred[1][wr*32 + m*16 + lg*4 + q][wc] = p2;
            }
        }
    }
    __syncthreads();
    if (t < 128){
        int row = t & 63, f = t >> 6;
        float v = fred[f][row][0] + fred[f][row][1] + fred[f][row][2] + fred[f][row][3];
        (f ? f2 : f1)[i0 + row] = v;
    }
}

// ---------------------------------------------------------------- spart[b][it][j] = sum_{i in it} adj ? exp(lrelu(f1_i+f2_j)) : 0
__global__ void spass(const unsigned* __restrict__ packed, const float* __restrict__ f1,
                      const float* __restrict__ f2, float* __restrict__ spart){
    __shared__ float sred[4][512];
    int jt = blockIdx.x, it = blockIdx.y, b = blockIdx.z;
    int t = threadIdx.x;
    int ti = t >> 6, jc = t & 63;
    int j0 = jt*512 + jc*8;
    const unsigned* pb = packed + (size_t)b*NN*NW;
    const float* f1b = f1 + b*NN;
    float f2v[8];
    *(float4*)&f2v[0] = *(const float4*)&f2[b*NN + j0];
    *(float4*)&f2v[4] = *(const float4*)&f2[b*NN + j0 + 4];
    int sh = (jc & 3) * 8;
    float acc[8] = {};
    for (int ii = 0; ii < 64; ++ii){
        int i = it*256 + ti*64 + ii;
        unsigned w = pb[(size_t)i*NW + (j0 >> 5)] >> sh;
        float f1v = f1b[i];
        #pragma unroll
        for (int e = 0; e < 8; ++e){
            float xv = f1v + f2v[e];
            float p = __expf(fmaxf(xv, ALPHA*xv));
            acc[e] += ((w >> e) & 1u) ? p : 0.f;
        }
    }
    #pragma unroll
    for (int e = 0; e < 8; ++e) sred[ti][jc*8 + e] = acc[e];
    __syncthreads();
    if (ti == 0){
        #pragma unroll
        for (int e = 0; e < 8; ++e){
            float s = sred[0][jc*8+e] + sred[1][jc*8+e] + sred[2][jc*8+e] + sred[3][jc*8+e];
            spart[((size_t)b*8 + it)*NN + j0 + e] = s;
        }
    }
}

// ---------------------------------------------------------------- E[i][j] = adj ? exp(lrelu(f1+f2) - ln s_j) : 0  (f16, normalized)
__global__ void epass(const unsigned* __restrict__ packed, const float* __restrict__ f1,
                      const float* __restrict__ f2, const float* __restrict__ spart,
                      _Float16* __restrict__ E){
    int it = blockIdx.x, b = blockIdx.y;
    int t = threadIdx.x;
    int j0 = t*8;
    float f2v[8], gv[8];
    *(float4*)&f2v[0] = *(const float4*)&f2[b*NN + j0];
    *(float4*)&f2v[4] = *(const float4*)&f2[b*NN + j0 + 4];
    float sa[8] = {};
    #pragma unroll
    for (int p8 = 0; p8 < 8; ++p8){
        float4 v0 = *(const float4*)&spart[((size_t)b*8 + p8)*NN + j0];
        float4 v1 = *(const float4*)&spart[((size_t)b*8 + p8)*NN + j0 + 4];
        sa[0] += v0.x; sa[1] += v0.y; sa[2] += v0.z; sa[3] += v0.w;
        sa[4] += v1.x; sa[5] += v1.y; sa[6] += v1.z; sa[7] += v1.w;
    }
    #pragma unroll
    for (int e = 0; e < 8; ++e) gv[e] = -__logf(sa[e]);
    const unsigned* pb = packed + (size_t)b*NN*NW;
    const float* f1b = f1 + b*NN;
    int sh = (t & 3) * 8;
    int i0 = it*32;
    for (int ii = 0; ii < 32; ++ii){
        int i = i0 + ii;
        unsigned w = pb[(size_t)i*NW + (j0 >> 5)] >> sh;
        float f1v = f1b[i];
        f16x8 ev;
        #pragma unroll
        for (int e = 0; e < 8; ++e){
            float xv = f1v + f2v[e];
            float p = __expf(fmaxf(xv, ALPHA*xv) + gv[e]);
            ev[e] = (_Float16)(((w >> e) & 1u) ? p : 0.f);
        }
        *(int4*)&E[((size_t)b*NN + i)*NN + j0] = *(int4*)&ev;
    }
}

// ---------------------------------------------------------------- hout = lrelu( E @ WhT^T ): pure f16 GEMM
// tile 32 rows x 256 cols; 256 thr (4 waves = 4 col groups); grid 512: b = blk&7 (XCD-locality)
__global__ __launch_bounds__(256,2) void gemm_att(const _Float16* __restrict__ E,
        const _Float16* __restrict__ WhT, _Float16* __restrict__ hnext,
        float* __restrict__ out, int last){
    __shared__ char Bs[32*1024];
    int t = threadIdx.x, l = t & 63, wc = t >> 6;
    int lg = l >> 4, lr = l & 15;
    int b  = blockIdx.x & 7;
    int i0 = (blockIdx.x >> 3) * 32;
    const _Float16* Eb = E + ((size_t)b*NN + i0)*NN;
    const _Float16* WT = WhT + (size_t)b*FF*NN;
    f32x4 acc[2][4] = {};
    for (int ks = 0; ks < 32; ++ks){
        int j0 = ks*64;
        // issue global loads first (B stage regs + A fragments), then overlap with prior ds phase
        int4 stg[8];
        #pragma unroll
        for (int q = 0; q < 8; ++q){
            int idx = q*256 + t;
            int col = idx >> 3, ch = idx & 7;
            stg[q] = *(const int4*)&WT[(size_t)col*NN + j0 + ch*8];
        }
        f16x8 pa[2][2];
        #pragma unroll
        for (int m = 0; m < 2; ++m)
            #pragma unroll
            for (int kk = 0; kk < 2; ++kk){
                int4 v = *(const int4*)&Eb[(size_t)(m*16 + lr)*NN + j0 + kk*32 + lg*8];
                pa[m][kk] = *(f16x8*)&v;
            }
        __syncthreads();   // previous iteration's ds_reads complete
        #pragma unroll
        for (int q = 0; q < 8; ++q){
            int idx = q*256 + t;
            int col = idx >> 3, ch = idx & 7;
            *(int4*)(Bs + (col << 7) + ((ch << 4) ^ ((col & 7) << 4))) = stg[q];
        }
        __syncthreads();
        #pragma unroll
        for (int n = 0; n < 4; ++n){
            int col = wc*64 + n*16 + lr;
            #pragma unroll
            for (int kk = 0; kk < 2; ++kk){
                f16x8 bf = *(const f16x8*)(Bs + (col << 7) + ((kk*64 + lg*16) ^ ((col & 7) << 4)));
                #pragma unroll
                for (int m = 0; m < 2; ++m)
                    acc[m][n] = __builtin_amdgcn_mfma_f32_16x16x32_f16(pa[m][kk], bf, acc[m][n], 0, 0, 0);
            }
        }
    }
    size_t obase = (size_t)b*NN*FF;
    #pragma unroll
    for (int m = 0; m < 2; ++m){
        #pragma unroll
        for (int q = 0; q < 4; ++q){
            size_t row = i0 + m*16 + lg*4 + q;
            #pragma unroll
            for (int n = 0; n < 4; ++n){
                int col = wc*64 + n*16 + lr;
                float v = lrelu(acc[m][n][q]);
                if (last) out[obase + row*FF + col] = v;
                else      hnext[obase + row*FF + col] = (_Float16)v;
            }
        }
    }
}

// ----------------------------------------------------------------
extern "C" void kernel_launch(void* const* d_in, const int* in_sizes, int n_in,
                              void* d_out, int out_size, void* d_ws, size_t ws_size,
                              hipStream_t stream){
    const float* x     = (const float*)d_in[0];
    const int*   adj   = (const int*)  d_in[1];
    const float* W0    = (const float*)d_in[2];
    const float* Wrest = (const float*)d_in[3];
    const float* A     = (const float*)d_in[4];
    float* out = (float*)d_out;

    char* ws = (char*)d_ws;
    size_t off = 0;
    auto carve = [&](size_t bytes) -> void* {
        void* p = ws + off;
        off += (bytes + 255) & ~(size_t)255;
        return p;
    };
    unsigned long long* packed = (unsigned long long*)carve((size_t)BB*NN*NN/8);
    _Float16* E    = (_Float16*)carve((size_t)BB*NN*NN*2);    // 67 MB normalized attention
    _Float16* hA   = (_Float16*)carve((size_t)BB*NN*FF*2);
    _Float16* hB   = (_Float16*)carve((size_t)BB*NN*FF*2);
    _Float16* WhT  = (_Float16*)carve((size_t)BB*NN*FF*2);
    _Float16* Wt   = (_Float16*)carve((size_t)4*FF*FF*2);
    float* f1    = (float*)carve((size_t)BB*NN*4);
    float* f2    = (float*)carve((size_t)BB*NN*4);
    float* spart = (float*)carve((size_t)BB*8*NN*4);

    pack_adj<<<2048, 256, 0, stream>>>(adj, packed, x, hA);
    prep_w<<<dim3(4,4,4), 256, 0, stream>>>(W0, Wrest, Wt);

    _Float16* bufs[2] = {hA, hB};
    const _Float16* hin = hA;
    for (int layer = 0; layer < 4; ++layer){
        const float* Al = A + (size_t)layer*2*FF;
        gemm_hw<<<256, 512, 0, stream>>>(hin, Wt + (size_t)layer*FF*FF, Al, WhT, f1, f2);
        spass<<<dim3(4,8,8), 256, 0, stream>>>((const unsigned*)packed, f1, f2, spart);
        epass<<<dim3(64,8), 256, 0, stream>>>((const unsigned*)packed, f1, f2, spart, E);
        int last = (layer == 3);
        _Float16* hnext = bufs[(layer + 1) & 1];
        gemm_att<<<512, 256, 0, stream>>>(E, WhT, hnext, out, last);
        hin = hnext;
    }
}

// Round 5
// 479.951 us; speedup vs baseline: 2.0524x; 2.0345x over previous
//
#include <hip/hip_runtime.h>
#include <math.h>

#define BB 8
#define NN 2048
#define FF 256
#define NW 64            // packed u32 words per adjacency row
#define ALPHA 0.2f

typedef _Float16 f16x8 __attribute__((ext_vector_type(8)));
typedef _Float16 f16x4 __attribute__((ext_vector_type(4)));
typedef float    f32x4 __attribute__((ext_vector_type(4)));

__device__ __forceinline__ float lrelu(float x){ return fmaxf(x, ALPHA*x); }

// ---------------------------------------------------------------- pack adj bits + x->f16
__global__ void pack_adj(const int* __restrict__ adj, unsigned long long* __restrict__ packed,
                         const float* __restrict__ x, _Float16* __restrict__ h0){
    long long idx = (long long)blockIdx.x*blockDim.x + threadIdx.x;
    long long stride = (long long)gridDim.x*blockDim.x;
    const long long total = (long long)BB*NN*NN;
    for (long long i = idx; i < total; i += stride){
        unsigned long long m = __ballot(adj[i] > 0);
        if ((threadIdx.x & 63) == 0) packed[i >> 6] = m;
    }
    const long long nx4 = (long long)BB*NN*FF/4;
    for (long long i = idx; i < nx4; i += stride){
        float4 v = ((const float4*)x)[i];
        union { _Float16 h[4]; unsigned long long u; } cv;
        cv.h[0] = (_Float16)v.x; cv.h[1] = (_Float16)v.y;
        cv.h[2] = (_Float16)v.z; cv.h[3] = (_Float16)v.w;
        ((unsigned long long*)h0)[i] = cv.u;
    }
}

// ---------------------------------------------------------------- W (fp32 [k][c]) -> Wt (f16 [c][k]), 4 layers
__global__ void prep_w(const float* __restrict__ W0, const float* __restrict__ Wrest,
                       _Float16* __restrict__ Wt){
    __shared__ _Float16 Ls[64][66];
    int layer = blockIdx.z;
    int c0 = blockIdx.x * 64, k0 = blockIdx.y * 64;
    const float* Win = (layer == 0) ? W0 : (Wrest + (size_t)(layer-1)*FF*FF);
    int t = threadIdx.x;
    for (int it = 0; it < 4; ++it){
        int idx = it*256 + t;
        int r = idx >> 4, c4 = (idx & 15) * 4;
        float4 v = *(const float4*)&Win[(size_t)(k0 + r)*FF + c0 + c4];
        Ls[c4+0][r] = (_Float16)v.x; Ls[c4+1][r] = (_Float16)v.y;
        Ls[c4+2][r] = (_Float16)v.z; Ls[c4+3][r] = (_Float16)v.w;
    }
    __syncthreads();
    int c = t >> 2, jch = t & 3;
    const unsigned* lp = (const unsigned*)&Ls[c][jch*16];
    int4 o0 = make_int4(lp[0], lp[1], lp[2], lp[3]);
    int4 o1 = make_int4(lp[4], lp[5], lp[6], lp[7]);
    _Float16* dst = Wt + ((size_t)layer*FF + c0 + c)*FF + k0 + jch*16;
    *(int4*)dst = o0;
    *(int4*)(dst + 8) = o1;
}

// ---------------------------------------------------------------- WhT = (h @ W)^T (f16 MFMA) + fused f1,f2
__global__ __launch_bounds__(512,2) void gemm_hw(const _Float16* __restrict__ hin,
        const _Float16* __restrict__ Wt, const float* __restrict__ Avec,
        _Float16* __restrict__ WhT, float* __restrict__ f1, float* __restrict__ f2){
    __shared__ float fred[2][64][4];
    int t = threadIdx.x, l = t & 63, wid = t >> 6;
    int wr = wid >> 2, wc = wid & 3;
    int lg = l >> 4, lr = l & 15;
    size_t i0 = (size_t)blockIdx.x * 64;
    f32x4 acc[2][4] = {};
    for (int k0 = 0; k0 < FF; k0 += 32){
        f16x8 a[2], bf[4];
        #pragma unroll
        for (int m = 0; m < 2; ++m){
            int4 v = *(const int4*)&hin[(i0 + wr*32 + m*16 + lr)*FF + k0 + lg*8];
            a[m] = *(f16x8*)&v;
        }
        #pragma unroll
        for (int n = 0; n < 4; ++n){
            int4 v = *(const int4*)&Wt[(size_t)(wc*64 + n*16 + lr)*FF + k0 + lg*8];
            bf[n] = *(f16x8*)&v;
        }
        #pragma unroll
        for (int m = 0; m < 2; ++m)
            #pragma unroll
            for (int n = 0; n < 4; ++n)
                acc[m][n] = __builtin_amdgcn_mfma_f32_16x16x32_f16(a[m], bf[n], acc[m][n], 0, 0, 0);
    }
    // transposed store: WhT[b][col][row] (f16x4 along rows)
    int b  = (int)(i0 >> 11);
    int jb = (int)(i0 & (NN-1));
    _Float16* WT = WhT + (size_t)b*FF*NN;
    #pragma unroll
    for (int m = 0; m < 2; ++m){
        #pragma unroll
        for (int n = 0; n < 4; ++n){
            int col = wc*64 + n*16 + lr;
            int row = jb + wr*32 + m*16 + lg*4;
            f16x4 pk;
            pk[0] = (_Float16)acc[m][n][0]; pk[1] = (_Float16)acc[m][n][1];
            pk[2] = (_Float16)acc[m][n][2]; pk[3] = (_Float16)acc[m][n][3];
            *(f16x4*)&WT[(size_t)col*NN + row] = pk;
        }
    }
    // fused f1/f2 (fp32 from accumulators)
    float a1v[4], a2v[4];
    #pragma unroll
    for (int n = 0; n < 4; ++n){
        a1v[n] = Avec[wc*64 + n*16 + lr];
        a2v[n] = Avec[FF + wc*64 + n*16 + lr];
    }
    #pragma unroll
    for (int m = 0; m < 2; ++m){
        #pragma unroll
        for (int q = 0; q < 4; ++q){
            float p1 = 0.f, p2 = 0.f;
            #pragma unroll
            for (int n = 0; n < 4; ++n){
                float v = acc[m][n][q];
                p1 = fmaf(v, a1v[n], p1);
                p2 = fmaf(v, a2v[n], p2);
            }
            #pragma unroll
            for (int msk = 1; msk < 16; msk <<= 1){
                p1 += __shfl_xor(p1, msk);
                p2 += __shfl_xor(p2, msk);
            }
            if (lr == 0){
                fred[0][wr*32 + m*16 + lg*4 + q][wc] = p1;
                fred[1][wr*32 + m*16 + lg*4 + q][wc] = p2;
            }
        }
    }
    __syncthreads();
    if (t < 128){
        int row = t & 63, f = t >> 6;
        float v = fred[f][row][0] + fred[f][row][1] + fred[f][row][2] + fred[f][row][3];
        (f ? f2 : f1)[i0 + row] = v;
    }
}

// ---------------------------------------------------------------- spart[b][it][j] = sum_{i in it} adj ? exp(lrelu(f1_i+f2_j)) : 0
__global__ void spass(const unsigned* __restrict__ packed, const float* __restrict__ f1,
                      const float* __restrict__ f2, float* __restrict__ spart){
    __shared__ float sred[4][512];
    int jt = blockIdx.x, it = blockIdx.y, b = blockIdx.z;
    int t = threadIdx.x;
    int ti = t >> 6, jc = t & 63;
    int j0 = jt*512 + jc*8;
    const unsigned* pb = packed + (size_t)b*NN*NW;
    const float* f1b = f1 + b*NN;
    float f2v[8];
    *(float4*)&f2v[0] = *(const float4*)&f2[b*NN + j0];
    *(float4*)&f2v[4] = *(const float4*)&f2[b*NN + j0 + 4];
    int sh = (jc & 3) * 8;
    float acc[8] = {};
    for (int ii = 0; ii < 64; ++ii){
        int i = it*256 + ti*64 + ii;
        unsigned w = pb[(size_t)i*NW + (j0 >> 5)] >> sh;
        float f1v = f1b[i];
        #pragma unroll
        for (int e = 0; e < 8; ++e){
            float xv = f1v + f2v[e];
            float p = __expf(fmaxf(xv, ALPHA*xv));
            acc[e] += ((w >> e) & 1u) ? p : 0.f;
        }
    }
    #pragma unroll
    for (int e = 0; e < 8; ++e) sred[ti][jc*8 + e] = acc[e];
    __syncthreads();
    if (ti == 0){
        #pragma unroll
        for (int e = 0; e < 8; ++e){
            float s = sred[0][jc*8+e] + sred[1][jc*8+e] + sred[2][jc*8+e] + sred[3][jc*8+e];
            spart[((size_t)b*8 + it)*NN + j0 + e] = s;
        }
    }
}

// ---------------------------------------------------------------- g[b][j] = -ln( sum_it spart )
__global__ void finish_g(const float* __restrict__ spart, float* __restrict__ g){
    int idx = blockIdx.x*256 + threadIdx.x;       // over B*N
    int b = idx >> 11, j = idx & (NN-1);
    float s = 0.f;
    #pragma unroll
    for (int it = 0; it < 8; ++it) s += spart[((size_t)b*8 + it)*NN + j];
    g[idx] = -__logf(s);
}

// ---------------------------------------------------------------- hout = lrelu( P @ WhT^T ), P built in LDS
// tile 64 rows x 256 cols; 512 thr (8 waves = 2 row-groups x 4 col-groups); grid 256: b = blk&7
__global__ __launch_bounds__(512,2) void gemm_att(const _Float16* __restrict__ WhT,
        const unsigned long long* __restrict__ packed64, const float* __restrict__ f1,
        const float* __restrict__ f2, const float* __restrict__ g,
        _Float16* __restrict__ hnext, float* __restrict__ out, int last){
    __shared__ char Bs[32*1024];
    __shared__ char Ps[8*1024];
    int t = threadIdx.x, l = t & 63, wid = t >> 6;
    int wr = wid >> 2, wc = wid & 3;
    int lg = l >> 4, lr = l & 15;
    int b  = blockIdx.x & 7;
    int i0 = (blockIdx.x >> 3) * 64;
    const _Float16* WT = WhT + (size_t)b*FF*NN;
    const unsigned long long* pb = packed64 + (size_t)b*NN*(NW/2);
    const float* f2b = f2 + b*NN;
    const float* gb  = g  + b*NN;
    // P-gen mapping: each thread owns (row = t>>3, 8 j's at (t&7)*8) of the 64x64 tile
    int prow = t >> 3;
    int pch  = t & 7;
    float f1v = f1[b*NN + i0 + prow];
    const unsigned long long* prowp = pb + (size_t)(i0 + prow)*(NW/2);
    char* pdst = Ps + prow*128 + ((pch << 4) ^ ((prow & 7) << 4));
    f32x4 acc[2][4] = {};
    for (int ks = 0; ks < 32; ++ks){
        int j0 = ks*64;
        __syncthreads();            // prior iteration's LDS reads done
        // ---- stage B: WhT[col][j0..j0+64) -> Bs (XOR-swizzled, round-2 proven)
        #pragma unroll
        for (int q = 0; q < 4; ++q){
            int idx = q*512 + t;
            int col = idx >> 3, ch = idx & 7;
            int4 v = *(const int4*)&WT[(size_t)col*NN + j0 + ch*8];
            *(int4*)(Bs + (col << 7) + ((ch << 4) ^ ((col & 7) << 4))) = v;
        }
        // ---- generate normalized P tile (64 rows x 64 j) into swizzled Ps
        {
            unsigned w8 = (unsigned)(prowp[ks] >> (pch*8)) & 0xffu;
            int jb = j0 + pch*8;
            float4 fa = *(const float4*)&f2b[jb];
            float4 fc = *(const float4*)&f2b[jb+4];
            float4 ga = *(const float4*)&gb[jb];
            float4 gc = *(const float4*)&gb[jb+4];
            float fv[8] = {fa.x,fa.y,fa.z,fa.w,fc.x,fc.y,fc.z,fc.w};
            float gv[8] = {ga.x,ga.y,ga.z,ga.w,gc.x,gc.y,gc.z,gc.w};
            f16x8 pv;
            #pragma unroll
            for (int e = 0; e < 8; ++e){
                float xv = f1v + fv[e];
                float p = __expf(fmaxf(xv, ALPHA*xv) + gv[e]);
                pv[e] = (_Float16)(((w8 >> e) & 1u) ? p : 0.f);
            }
            *(f16x8*)pdst = pv;
        }
        __syncthreads();
        // ---- A fragments from Ps (swizzled read; k = kk*32 + lg*8 + e)
        f16x8 pa[2][2];
        #pragma unroll
        for (int m = 0; m < 2; ++m){
            int row = wr*32 + m*16 + lr;
            #pragma unroll
            for (int kk = 0; kk < 2; ++kk)
                pa[m][kk] = *(const f16x8*)(Ps + row*128 + (((kk*4 + lg) << 4) ^ ((row & 7) << 4)));
        }
        // ---- B fragments + MFMA
        #pragma unroll
        for (int n = 0; n < 4; ++n){
            int col = wc*64 + n*16 + lr;
            #pragma unroll
            for (int kk = 0; kk < 2; ++kk){
                f16x8 bf = *(const f16x8*)(Bs + (col << 7) + ((kk*64 + lg*16) ^ ((col & 7) << 4)));
                #pragma unroll
                for (int m = 0; m < 2; ++m)
                    acc[m][n] = __builtin_amdgcn_mfma_f32_16x16x32_f16(pa[m][kk], bf, acc[m][n], 0, 0, 0);
            }
        }
    }
    size_t obase = (size_t)b*NN*FF;
    #pragma unroll
    for (int m = 0; m < 2; ++m){
        #pragma unroll
        for (int q = 0; q < 4; ++q){
            size_t row = i0 + wr*32 + m*16 + lg*4 + q;
            #pragma unroll
            for (int n = 0; n < 4; ++n){
                int col = wc*64 + n*16 + lr;
                float v = lrelu(acc[m][n][q]);
                if (last) out[obase + row*FF + col] = v;
                else      hnext[obase + row*FF + col] = (_Float16)v;
            }
        }
    }
}

// ----------------------------------------------------------------
extern "C" void kernel_launch(void* const* d_in, const int* in_sizes, int n_in,
                              void* d_out, int out_size, void* d_ws, size_t ws_size,
                              hipStream_t stream){
    const float* x     = (const float*)d_in[0];
    const int*   adj   = (const int*)  d_in[1];
    const float* W0    = (const float*)d_in[2];
    const float* Wrest = (const float*)d_in[3];
    const float* A     = (const float*)d_in[4];
    float* out = (float*)d_out;

    char* ws = (char*)d_ws;
    size_t off = 0;
    auto carve = [&](size_t bytes) -> void* {
        void* p = ws + off;
        off += (bytes + 255) & ~(size_t)255;
        return p;
    };
    unsigned long long* packed = (unsigned long long*)carve((size_t)BB*NN*NN/8);
    _Float16* hA   = (_Float16*)carve((size_t)BB*NN*FF*2);
    _Float16* hB   = (_Float16*)carve((size_t)BB*NN*FF*2);
    _Float16* WhT  = (_Float16*)carve((size_t)BB*NN*FF*2);
    _Float16* Wt   = (_Float16*)carve((size_t)4*FF*FF*2);
    float* f1    = (float*)carve((size_t)BB*NN*4);
    float* f2    = (float*)carve((size_t)BB*NN*4);
    float* g     = (float*)carve((size_t)BB*NN*4);
    float* spart = (float*)carve((size_t)BB*8*NN*4);

    pack_adj<<<2048, 256, 0, stream>>>(adj, packed, x, hA);
    prep_w<<<dim3(4,4,4), 256, 0, stream>>>(W0, Wrest, Wt);

    _Float16* bufs[2] = {hA, hB};
    const _Float16* hin = hA;
    for (int layer = 0; layer < 4; ++layer){
        const float* Al = A + (size_t)layer*2*FF;
        gemm_hw<<<256, 512, 0, stream>>>(hin, Wt + (size_t)layer*FF*FF, Al, WhT, f1, f2);
        spass<<<dim3(4,8,8), 256, 0, stream>>>((const unsigned*)packed, f1, f2, spart);
        finish_g<<<BB*NN/256, 256, 0, stream>>>(spart, g);
        int last = (layer == 3);
        _Float16* hnext = bufs[(layer + 1) & 1];
        gemm_att<<<256, 512, 0, stream>>>(WhT, packed, f1, f2, g, hnext, out, last);
        hin = hnext;
    }
}

// Round 6
// 391.292 us; speedup vs baseline: 2.5174x; 1.2266x over previous
//
#include <hip/hip_runtime.h>
#include <math.h>

#define BB 8
#define NN 2048
#define FF 256
#define NW 64            // packed u32 words per adjacency row
#define ALPHA 0.2f

typedef _Float16 f16x8 __attribute__((ext_vector_type(8)));
typedef _Float16 f16x4 __attribute__((ext_vector_type(4)));
typedef float    f32x4 __attribute__((ext_vector_type(4)));

__device__ __forceinline__ float lrelu(float x){ return fmaxf(x, ALPHA*x); }

// ---------------------------------------------------------------- pack adj bits + x->f16
__global__ void pack_adj(const int* __restrict__ adj, unsigned long long* __restrict__ packed,
                         const float* __restrict__ x, _Float16* __restrict__ h0){
    long long idx = (long long)blockIdx.x*blockDim.x + threadIdx.x;
    long long stride = (long long)gridDim.x*blockDim.x;
    const long long total = (long long)BB*NN*NN;
    for (long long i = idx; i < total; i += stride){
        unsigned long long m = __ballot(adj[i] > 0);
        if ((threadIdx.x & 63) == 0) packed[i >> 6] = m;
    }
    const long long nx4 = (long long)BB*NN*FF/4;
    for (long long i = idx; i < nx4; i += stride){
        float4 v = ((const float4*)x)[i];
        union { _Float16 h[4]; unsigned long long u; } cv;
        cv.h[0] = (_Float16)v.x; cv.h[1] = (_Float16)v.y;
        cv.h[2] = (_Float16)v.z; cv.h[3] = (_Float16)v.w;
        ((unsigned long long*)h0)[i] = cv.u;
    }
}

// ---------------------------------------------------------------- W (fp32 [k][c]) -> Wt (f16 [c][k]), 4 layers
__global__ void prep_w(const float* __restrict__ W0, const float* __restrict__ Wrest,
                       _Float16* __restrict__ Wt){
    __shared__ _Float16 Ls[64][66];
    int layer = blockIdx.z;
    int c0 = blockIdx.x * 64, k0 = blockIdx.y * 64;
    const float* Win = (layer == 0) ? W0 : (Wrest + (size_t)(layer-1)*FF*FF);
    int t = threadIdx.x;
    for (int it = 0; it < 4; ++it){
        int idx = it*256 + t;
        int r = idx >> 4, c4 = (idx & 15) * 4;
        float4 v = *(const float4*)&Win[(size_t)(k0 + r)*FF + c0 + c4];
        Ls[c4+0][r] = (_Float16)v.x; Ls[c4+1][r] = (_Float16)v.y;
        Ls[c4+2][r] = (_Float16)v.z; Ls[c4+3][r] = (_Float16)v.w;
    }
    __syncthreads();
    int c = t >> 2, jch = t & 3;
    const unsigned* lp = (const unsigned*)&Ls[c][jch*16];
    int4 o0 = make_int4(lp[0], lp[1], lp[2], lp[3]);
    int4 o1 = make_int4(lp[4], lp[5], lp[6], lp[7]);
    _Float16* dst = Wt + ((size_t)layer*FF + c0 + c)*FF + k0 + jch*16;
    *(int4*)dst = o0;
    *(int4*)(dst + 8) = o1;
}

// ---------------------------------------------------------------- WhT = (h @ W)^T (f16 MFMA) + fused f1,f2
__global__ __launch_bounds__(512,2) void gemm_hw(const _Float16* __restrict__ hin,
        const _Float16* __restrict__ Wt, const float* __restrict__ Avec,
        _Float16* __restrict__ WhT, float* __restrict__ f1, float* __restrict__ f2){
    __shared__ float fred[2][64][4];
    int t = threadIdx.x, l = t & 63, wid = t >> 6;
    int wr = wid >> 2, wc = wid & 3;
    int lg = l >> 4, lr = l & 15;
    size_t i0 = (size_t)blockIdx.x * 64;
    f32x4 acc[2][4] = {};
    for (int k0 = 0; k0 < FF; k0 += 32){
        f16x8 a[2], bf[4];
        #pragma unroll
        for (int m = 0; m < 2; ++m){
            int4 v = *(const int4*)&hin[(i0 + wr*32 + m*16 + lr)*FF + k0 + lg*8];
            a[m] = *(f16x8*)&v;
        }
        #pragma unroll
        for (int n = 0; n < 4; ++n){
            int4 v = *(const int4*)&Wt[(size_t)(wc*64 + n*16 + lr)*FF + k0 + lg*8];
            bf[n] = *(f16x8*)&v;
        }
        #pragma unroll
        for (int m = 0; m < 2; ++m)
            #pragma unroll
            for (int n = 0; n < 4; ++n)
                acc[m][n] = __builtin_amdgcn_mfma_f32_16x16x32_f16(a[m], bf[n], acc[m][n], 0, 0, 0);
    }
    // transposed store: WhT[b][col][row] (f16x4 along rows)
    int b  = (int)(i0 >> 11);
    int jb = (int)(i0 & (NN-1));
    _Float16* WT = WhT + (size_t)b*FF*NN;
    #pragma unroll
    for (int m = 0; m < 2; ++m){
        #pragma unroll
        for (int n = 0; n < 4; ++n){
            int col = wc*64 + n*16 + lr;
            int row = jb + wr*32 + m*16 + lg*4;
            f16x4 pk;
            pk[0] = (_Float16)acc[m][n][0]; pk[1] = (_Float16)acc[m][n][1];
            pk[2] = (_Float16)acc[m][n][2]; pk[3] = (_Float16)acc[m][n][3];
            *(f16x4*)&WT[(size_t)col*NN + row] = pk;
        }
    }
    // fused f1/f2 (fp32 from accumulators)
    float a1v[4], a2v[4];
    #pragma unroll
    for (int n = 0; n < 4; ++n){
        a1v[n] = Avec[wc*64 + n*16 + lr];
        a2v[n] = Avec[FF + wc*64 + n*16 + lr];
    }
    #pragma unroll
    for (int m = 0; m < 2; ++m){
        #pragma unroll
        for (int q = 0; q < 4; ++q){
            float p1 = 0.f, p2 = 0.f;
            #pragma unroll
            for (int n = 0; n < 4; ++n){
                float v = acc[m][n][q];
                p1 = fmaf(v, a1v[n], p1);
                p2 = fmaf(v, a2v[n], p2);
            }
            #pragma unroll
            for (int msk = 1; msk < 16; msk <<= 1){
                p1 += __shfl_xor(p1, msk);
                p2 += __shfl_xor(p2, msk);
            }
            if (lr == 0){
                fred[0][wr*32 + m*16 + lg*4 + q][wc] = p1;
                fred[1][wr*32 + m*16 + lg*4 + q][wc] = p2;
            }
        }
    }
    __syncthreads();
    if (t < 128){
        int row = t & 63, f = t >> 6;
        float v = fred[f][row][0] + fred[f][row][1] + fred[f][row][2] + fred[f][row][3];
        (f ? f2 : f1)[i0 + row] = v;
    }
}

// ---------------------------------------------------------------- spart[b][it][j] = sum_{i in it} adj ? exp(lrelu(f1_i+f2_j)) : 0
__global__ void spass(const unsigned* __restrict__ packed, const float* __restrict__ f1,
                      const float* __restrict__ f2, float* __restrict__ spart){
    __shared__ float sred[4][512];
    int jt = blockIdx.x, it = blockIdx.y, b = blockIdx.z;
    int t = threadIdx.x;
    int ti = t >> 6, jc = t & 63;
    int j0 = jt*512 + jc*8;
    const unsigned* pb = packed + (size_t)b*NN*NW;
    const float* f1b = f1 + b*NN;
    float f2v[8];
    *(float4*)&f2v[0] = *(const float4*)&f2[b*NN + j0];
    *(float4*)&f2v[4] = *(const float4*)&f2[b*NN + j0 + 4];
    int sh = (jc & 3) * 8;
    float acc[8] = {};
    for (int ii = 0; ii < 64; ++ii){
        int i = it*256 + ti*64 + ii;
        unsigned w = pb[(size_t)i*NW + (j0 >> 5)] >> sh;
        float f1v = f1b[i];
        #pragma unroll
        for (int e = 0; e < 8; ++e){
            float xv = f1v + f2v[e];
            float p = __expf(fmaxf(xv, ALPHA*xv));
            acc[e] += ((w >> e) & 1u) ? p : 0.f;
        }
    }
    #pragma unroll
    for (int e = 0; e < 8; ++e) sred[ti][jc*8 + e] = acc[e];
    __syncthreads();
    if (ti == 0){
        #pragma unroll
        for (int e = 0; e < 8; ++e){
            float s = sred[0][jc*8+e] + sred[1][jc*8+e] + sred[2][jc*8+e] + sred[3][jc*8+e];
            spart[((size_t)b*8 + it)*NN + j0 + e] = s;
        }
    }
}

// ---------------------------------------------------------------- g[b][j] = -ln( sum_it spart )
__global__ void finish_g(const float* __restrict__ spart, float* __restrict__ g){
    int idx = blockIdx.x*256 + threadIdx.x;       // over B*N
    int b = idx >> 11, j = idx & (NN-1);
    float s = 0.f;
    #pragma unroll
    for (int it = 0; it < 8; ++it) s += spart[((size_t)b*8 + it)*NN + j];
    g[idx] = -__logf(s);
}

// ---------------------------------------------------------------- hout = lrelu( P @ WhT^T ), P built in LDS
// 2-phase pipelined: double-buffered Bs/Ps, 1 barrier per K-step, loads issued a step ahead.
// tile 64 rows x 256 cols; 512 thr (8 waves = 2 row-groups x 4 col-groups); grid 256: b = blk&7
__global__ __launch_bounds__(512,2) void gemm_att(const _Float16* __restrict__ WhT,
        const unsigned long long* __restrict__ packed64, const float* __restrict__ f1,
        const float* __restrict__ f2, const float* __restrict__ g,
        _Float16* __restrict__ hnext, float* __restrict__ out, int last){
    __shared__ char Bs[2][32*1024];
    __shared__ char Ps[2][8*1024];
    int t = threadIdx.x, l = t & 63, wid = t >> 6;
    int wr = wid >> 2, wc = wid & 3;
    int lg = l >> 4, lr = l & 15;
    int b  = blockIdx.x & 7;
    int i0 = (blockIdx.x >> 3) * 64;
    const _Float16* WT = WhT + (size_t)b*FF*NN;
    const unsigned long long* pb = packed64 + (size_t)b*NN*(NW/2);
    const float* f2b = f2 + b*NN;
    const float* gb  = g  + b*NN;
    // P-gen mapping: thread owns (row = t>>3, 8 j's at (t&7)*8) of the 64x64 P tile
    int prow = t >> 3;
    int pch  = t & 7;
    float f1v = f1[b*NN + i0 + prow];
    const unsigned long long* prowp = pb + (size_t)(i0 + prow)*(NW/2);
    int pso = prow*128 + ((pch << 4) ^ ((prow & 7) << 4));
    int bcol = t >> 3, bch = t & 7;    // B-stage mapping: col = q*64 + bcol, chunk bch

    int4 bstg[4];
    float fv[8], gv[8];
    unsigned w8;

    // issue next-tile loads (global; latency hidden under MFMA of current tile)
    #define STAGE_LOAD(ks_) do{ int j0_ = (ks_)*64;                                   \
        _Pragma("unroll")                                                             \
        for (int q = 0; q < 4; ++q){                                                  \
            int col_ = q*64 + bcol;                                                   \
            bstg[q] = *(const int4*)&WT[(size_t)col_*NN + j0_ + bch*8];               \
        }                                                                             \
        w8 = (unsigned)(prowp[ks_] >> (pch*8)) & 0xffu;                               \
        int jb_ = j0_ + pch*8;                                                        \
        *(float4*)&fv[0] = *(const float4*)&f2b[jb_];                                 \
        *(float4*)&fv[4] = *(const float4*)&f2b[jb_+4];                               \
        *(float4*)&gv[0] = *(const float4*)&gb[jb_];                                  \
        *(float4*)&gv[4] = *(const float4*)&gb[jb_+4];                                \
    }while(0)

    // compute P (exp) + write staged B/P into buffer buf_
    #define STAGE_WRITE(buf_) do{                                                     \
        f16x8 pv_;                                                                    \
        _Pragma("unroll")                                                             \
        for (int e = 0; e < 8; ++e){                                                  \
            float xv_ = f1v + fv[e];                                                  \
            float p_ = __expf(fmaxf(xv_, ALPHA*xv_) + gv[e]);                         \
            pv_[e] = (_Float16)(((w8 >> e) & 1u) ? p_ : 0.f);                         \
        }                                                                             \
        *(f16x8*)(Ps[buf_] + pso) = pv_;                                              \
        _Pragma("unroll")                                                             \
        for (int q = 0; q < 4; ++q){                                                  \
            int col_ = q*64 + bcol;                                                   \
            *(int4*)(Bs[buf_] + (col_ << 7) + ((bch << 4) ^ ((col_ & 7) << 4))) = bstg[q]; \
        }                                                                             \
    }while(0)

    f32x4 acc[2][4] = {};
    STAGE_LOAD(0);
    STAGE_WRITE(0);
    __syncthreads();
    for (int ks = 0; ks < 32; ++ks){
        int cur = ks & 1;
        if (ks < 31) STAGE_LOAD(ks+1);
        // ---- A fragments from Ps[cur] (swizzled), B from Bs[cur], MFMA
        f16x8 pa[2][2];
        #pragma unroll
        for (int m = 0; m < 2; ++m){
            int row = wr*32 + m*16 + lr;
            #pragma unroll
            for (int kk = 0; kk < 2; ++kk)
                pa[m][kk] = *(const f16x8*)(Ps[cur] + row*128 + (((kk*4 + lg) << 4) ^ ((row & 7) << 4)));
        }
        #pragma unroll
        for (int n = 0; n < 4; ++n){
            int col = wc*64 + n*16 + lr;
            #pragma unroll
            for (int kk = 0; kk < 2; ++kk){
                f16x8 bf = *(const f16x8*)(Bs[cur] + (col << 7) + ((kk*64 + lg*16) ^ ((col & 7) << 4)));
                #pragma unroll
                for (int m = 0; m < 2; ++m)
                    acc[m][n] = __builtin_amdgcn_mfma_f32_16x16x32_f16(pa[m][kk], bf, acc[m][n], 0, 0, 0);
            }
        }
        if (ks < 31) STAGE_WRITE(cur ^ 1);   // writes the OTHER buffer: no hazard with this step's reads
        __syncthreads();                      // orders write -> next step's reads
    }
    size_t obase = (size_t)b*NN*FF;
    #pragma unroll
    for (int m = 0; m < 2; ++m){
        #pragma unroll
        for (int q = 0; q < 4; ++q){
            size_t row = i0 + wr*32 + m*16 + lg*4 + q;
            #pragma unroll
            for (int n = 0; n < 4; ++n){
                int col = wc*64 + n*16 + lr;
                float v = lrelu(acc[m][n][q]);
                if (last) out[obase + row*FF + col] = v;
                else      hnext[obase + row*FF + col] = (_Float16)v;
            }
        }
    }
    #undef STAGE_LOAD
    #undef STAGE_WRITE
}

// ----------------------------------------------------------------
extern "C" void kernel_launch(void* const* d_in, const int* in_sizes, int n_in,
                              void* d_out, int out_size, void* d_ws, size_t ws_size,
                              hipStream_t stream){
    const float* x     = (const float*)d_in[0];
    const int*   adj   = (const int*)  d_in[1];
    const float* W0    = (const float*)d_in[2];
    const float* Wrest = (const float*)d_in[3];
    const float* A     = (const float*)d_in[4];
    float* out = (float*)d_out;

    char* ws = (char*)d_ws;
    size_t off = 0;
    auto carve = [&](size_t bytes) -> void* {
        void* p = ws + off;
        off += (bytes + 255) & ~(size_t)255;
        return p;
    };
    unsigned long long* packed = (unsigned long long*)carve((size_t)BB*NN*NN/8);
    _Float16* hA   = (_Float16*)carve((size_t)BB*NN*FF*2);
    _Float16* hB   = (_Float16*)carve((size_t)BB*NN*FF*2);
    _Float16* WhT  = (_Float16*)carve((size_t)BB*NN*FF*2);
    _Float16* Wt   = (_Float16*)carve((size_t)4*FF*FF*2);
    float* f1    = (float*)carve((size_t)BB*NN*4);
    float* f2    = (float*)carve((size_t)BB*NN*4);
    float* g     = (float*)carve((size_t)BB*NN*4);
    float* spart = (float*)carve((size_t)BB*8*NN*4);

    pack_adj<<<2048, 256, 0, stream>>>(adj, packed, x, hA);
    prep_w<<<dim3(4,4,4), 256, 0, stream>>>(W0, Wrest, Wt);

    _Float16* bufs[2] = {hA, hB};
    const _Float16* hin = hA;
    for (int layer = 0; layer < 4; ++layer){
        const float* Al = A + (size_t)layer*2*FF;
        gemm_hw<<<256, 512, 0, stream>>>(hin, Wt + (size_t)layer*FF*FF, Al, WhT, f1, f2);
        spass<<<dim3(4,8,8), 256, 0, stream>>>((const unsigned*)packed, f1, f2, spart);
        finish_g<<<BB*NN/256, 256, 0, stream>>>(spart, g);
        int last = (layer == 3);
        _Float16* hnext = bufs[(layer + 1) & 1];
        gemm_att<<<256, 512, 0, stream>>>(WhT, packed, f1, f2, g, hnext, out, last);
        hin = hnext;
    }
}